// Round 6
// baseline (517.925 us; speedup 1.0000x reference)
//
#include <hip/hip_runtime.h>
#include <hip/hip_bf16.h>
#include <cstdint>

#define EPS_BN 1e-5f

typedef __attribute__((ext_vector_type(8)))  short bf16x8;   // 8 bf16 = 4 VGPRs
typedef __attribute__((ext_vector_type(16))) float f32x16;   // MFMA 32x32 acc
typedef __attribute__((ext_vector_type(4)))  unsigned short u16x4;

#define MFMA32(a, b, c) __builtin_amdgcn_mfma_f32_32x32x16_bf16(a, b, c, 0, 0, 0)

// ---------------------------------------------------------------------------
// build transposed inverted map: invT[k*n_down + s] = g  (s unique per k).
// Table pre-memset to 0xFF (-1 = miss).
// ---------------------------------------------------------------------------
__global__ void build_inv(const int* __restrict__ gather, const int* __restrict__ scatter,
                          long total, int m, int* __restrict__ invT, int n_down) {
    long i = (long)blockIdx.x * blockDim.x + threadIdx.x;
    if (i >= total) return;
    int s = scatter[i];
    if (s < n_down) {
        int k = (int)(i / m);
        invT[(long)k * n_down + s] = gather[i];
    }
}

// feat f32[n_in][32] -> bf16 [n_in+1][32] (pad row zero); also zero ybf pad row.
__global__ void fcvt(const float* __restrict__ f, unsigned short* __restrict__ fb,
                     unsigned short* __restrict__ ybf_pad, long n_in) {
    long t = (long)blockIdx.x * blockDim.x + threadIdx.x;
    long e = t * 4;
    long total = n_in * 32;
    if (e < total) {
        float4 v = *(const float4*)(f + e);
        u16x4 o;
        __hip_bfloat16 h;
        h = __float2bfloat16(v.x); o.x = *(unsigned short*)&h;
        h = __float2bfloat16(v.y); o.y = *(unsigned short*)&h;
        h = __float2bfloat16(v.z); o.z = *(unsigned short*)&h;
        h = __float2bfloat16(v.w); o.w = *(unsigned short*)&h;
        *(u16x4*)(fb + e) = o;
    } else if (e < total + 32) {
        u16x4 z = {0, 0, 0, 0};
        *(u16x4*)(fb + e) = z;
    }
    if (blockIdx.x == 0 && threadIdx.x < 16) {
        u16x4 z = {0, 0, 0, 0};
        ((u16x4*)ybf_pad)[threadIdx.x] = z;
    }
}

// w_ref f32[81][64cin][64cout] -> bf16 wt[k][kq(4)][col(64)][16]: slot
// (col, lhi*8+j) of kq holds w[cin = kq*16+lhi*8+j][col] -> one coalesced b128
// per (kq, ntile) B-fragment load.
__global__ void wcvt_r(const float* __restrict__ w, unsigned short* __restrict__ wt) {
    int e = blockIdx.x * 256 + threadIdx.x;      // 81*4096
    int k = e >> 12, r = e & 4095;
    int cin = ((r >> 10) << 4) + (r & 15);
    int col = (r >> 4) & 63;
    __hip_bfloat16 h = __float2bfloat16(w[(k << 12) + (cin << 6) + col]);
    wt[e] = *(unsigned short*)&h;
}

// w_down f32[16][32cin][64cout] -> bf16 wtd[k][kq(2)][col(64)][16]
__global__ void wcvt_d(const float* __restrict__ w, unsigned short* __restrict__ wt) {
    int e = blockIdx.x * 256 + threadIdx.x;      // 16*2048
    int k = e >> 11, r = e & 2047;
    int cin = ((r >> 10) << 4) + (r & 15);
    int col = (r >> 4) & 63;
    __hip_bfloat16 h = __float2bfloat16(w[(k << 11) + (cin << 6) + col]);
    wt[e] = *(unsigned short*)&h;
}

// ---------------------------------------------------------------------------
// Stage 1: MFMA bf16, K=32, one wave = 32 rows. 91% pad-row gathers (L1-hot).
// ---------------------------------------------------------------------------
__global__ __launch_bounds__(256, 4) void conv_down_mfma(
        const unsigned short* __restrict__ fb, const unsigned short* __restrict__ wtd,
        const int* __restrict__ invd,
        const float* __restrict__ gamma, const float* __restrict__ beta,
        const float* __restrict__ mean, const float* __restrict__ var,
        unsigned short* __restrict__ y, int n_down, int n_in) {
    int  tid  = threadIdx.x;
    int  lane = tid & 63, l31 = lane & 31, lhi = lane >> 5;
    long wv   = ((long)blockIdx.x * 256 + tid) >> 6;
    long o0   = wv * 32;
    if (o0 >= n_down) return;

    int  oA = (int)(o0 + l31 < n_down ? o0 + l31 : n_down - 1);
    const short* ysb = (const short*)fb;

#define LDI_D(k) invd[(size_t)(k) * n_down + oA]
#define GATH_D(dst, g) { \
        const short* p = ysb + (size_t)((g) < 0 ? n_in : (g)) * 32 + lhi * 8; \
        dst[0] = *(const bf16x8*)p; dst[1] = *(const bf16x8*)(p + 16); }

    int g0 = LDI_D(0), gq1 = LDI_D(1), gq2 = LDI_D(2);
    bf16x8 ac[2];
    GATH_D(ac, g0);
    f32x16 acc0 = {}, acc1 = {};
    const short* wp = (const short*)wtd + l31 * 16 + lhi * 8;

    for (int k = 0; k < 16; ++k) {
        int gN = (k < 13) ? LDI_D(k + 3) : -1;
        bf16x8 an[2];
        GATH_D(an, gq1);
        const short* wk = wp + k * 2048;
#pragma unroll
        for (int kq = 0; kq < 2; ++kq) {
            bf16x8 b0 = *(const bf16x8*)(wk + kq * 1024);
            bf16x8 b1 = *(const bf16x8*)(wk + kq * 1024 + 512);
            acc0 = MFMA32(ac[kq], b0, acc0);
            acc1 = MFMA32(ac[kq], b1, acc1);
        }
        ac[0] = an[0]; ac[1] = an[1];
        gq1 = gq2; gq2 = gN;
    }

#pragma unroll
    for (int n = 0; n < 2; ++n) {
        int col = n * 32 + l31;
        float iv = gamma[col] * rsqrtf(var[col] + EPS_BN);
        float bb = beta[col] - mean[col] * iv;
        const f32x16& A = n ? acc1 : acc0;
#pragma unroll
        for (int i = 0; i < 16; ++i) {
            long oo = o0 + (i & 3) + 8 * (i >> 2) + 4 * lhi;
            if (oo < n_down) {
                __hip_bfloat16 h = __float2bfloat16(fmaxf(A[i] * iv + bb, 0.f));
                y[oo * 64 + col] = *(unsigned short*)&h;
            }
        }
    }
#undef LDI_D
#undef GATH_D
}

// ---------------------------------------------------------------------------
// Stage 2: MFMA bf16, wave = 64 rows x 64 cols, 81 offsets. ZERO LDS:
// A gathered DIRECTLY global->VGPR as MFMA fragments (lane l loads its own
// row idx invr[k*n + o0+l31] -- no shuffle; frag kq at row*128 + kq*32 +
// lhi*16). B global->reg. Both double-buffered in NAMED register sets via
// unroll-2 (rule #20); barrier-free per-wave pipeline (R4 discipline, the
// best-measured structure); compiler places counted waits for reg loads.
// State: A 64 + B 64 VGPR + 64 AGPR acc -> 2 waves/SIMD.
// ---------------------------------------------------------------------------
__global__ __launch_bounds__(256, 2) void conv_ref_mfma(
        const unsigned short* __restrict__ ybf, const unsigned short* __restrict__ wt,
        const int* __restrict__ invr,
        const float* __restrict__ gamma, const float* __restrict__ beta,
        const float* __restrict__ mean, const float* __restrict__ var,
        float* __restrict__ out, int n_down, int nwg) {
    // bijective XCD swizzle (m204)
    int bid = blockIdx.x;
    int q = nwg >> 3, r = nwg & 7;
    int xcd = bid & 7, pos = bid >> 3;
    int swzb = (xcd < r ? xcd * (q + 1) : r * (q + 1) + (xcd - r) * q) + pos;

    const int tid  = threadIdx.x;
    const int lane = tid & 63, l31 = lane & 31, lhi = lane >> 5;
    const int wid  = tid >> 6;
    const long o0  = ((long)swzb * 4 + wid) * 64;
    if (o0 >= n_down) return;

    // per-lane idx addresses (clamped tail reads valid memory; stores guarded)
    const int oLa = (int)(o0 + l31      < n_down ? o0 + l31      : n_down - 1);
    const int oLb = (int)(o0 + 32 + l31 < n_down ? o0 + 32 + l31 : n_down - 1);
    const char* ybase = (const char*)ybf;

#define LDI(k, ga, gb) { const int* p = invr + (size_t)(k) * n_down; \
                         ga = p[oLa]; gb = p[oLb]; }

    // A fragments: lane holds rows (o-tile row l31) and (32+l31); frag kq =
    // 16B at row*128 + kq*32 + lhi*16.
#define GATH(A, ga, gb) { \
        const char* pa_ = ybase + (size_t)((ga) < 0 ? n_down : (ga)) * 128 + lhi * 16; \
        const char* pb_ = ybase + (size_t)((gb) < 0 ? n_down : (gb)) * 128 + lhi * 16; \
        _Pragma("unroll") \
        for (int kq = 0; kq < 4; ++kq) { \
            A##a[kq] = *(const bf16x8*)(pa_ + kq * 32); \
            A##b[kq] = *(const bf16x8*)(pb_ + kq * 32); } }

#define LDB(B, k) { \
        const short* wk_ = wp + (size_t)(k) * 4096; \
        _Pragma("unroll") \
        for (int kq = 0; kq < 4; ++kq) { \
            B##0[kq] = *(const bf16x8*)(wk_ + kq * 1024); \
            B##1[kq] = *(const bf16x8*)(wk_ + kq * 1024 + 512); } }

#define COMPUTE(A, B) { \
        __builtin_amdgcn_s_setprio(1); \
        _Pragma("unroll") \
        for (int kq = 0; kq < 4; ++kq) { \
            acc0 = MFMA32(A##a[kq], B##0[kq], acc0); \
            acc1 = MFMA32(A##a[kq], B##1[kq], acc1); \
            acc2 = MFMA32(A##b[kq], B##0[kq], acc2); \
            acc3 = MFMA32(A##b[kq], B##1[kq], acc3); } \
        __builtin_amdgcn_s_setprio(0); }

    f32x16 acc0 = {}, acc1 = {}, acc2 = {}, acc3 = {};
    const short* wp = (const short*)wt + l31 * 16 + lhi * 8;

    bf16x8 Aca[4], Acb[4], Ana[4], Anb[4];   // A cur / next (named sets)
    bf16x8 Bc0[4], Bc1[4], Bn0[4], Bn1[4];   // B cur / next

    // prologue: idx 0..3 in flight; A[0],B[0] -> cur
    int g0a, g0b, g1a, g1b, g2a, g2b, g3a, g3b;
    LDI(0, g0a, g0b);
    LDI(1, g1a, g1b);
    LDI(2, g2a, g2b);
    LDI(3, g3a, g3b);
    GATH(Ac, g0a, g0b);
    LDB(Bc, 0);

    // main loop: regions k, k+1 per iteration; idx prefetch distance 3
    for (int k = 0; k < 80; k += 2) {
        int t1a, t1b, t2a, t2b;
        // region k: prefetch A[k+1]/B[k+1] + idx[k+4]; compute cur
        GATH(An, g1a, g1b);
        LDB(Bn, k + 1);
        LDI(k + 4, t1a, t1b);
        COMPUTE(Ac, Bc);
        // region k+1: prefetch A[k+2]/B[k+2] + idx[k+5]; compute next
        GATH(Ac, g2a, g2b);
        LDB(Bc, k + 2);
        if (k < 76) { LDI(k + 5, t2a, t2b); } else { t2a = -1; t2b = -1; }
        COMPUTE(An, Bn);
        g1a = g3a; g1b = g3b;                 // shift idx queue by 2
        g2a = t1a; g2b = t1b;
        g3a = t2a; g3b = t2b;
    }
    COMPUTE(Ac, Bc);                          // k = 80 (A/B already resident)

    // epilogue: BN + ReLU, f32 out
#pragma unroll
    for (int m = 0; m < 2; ++m)
#pragma unroll
        for (int n = 0; n < 2; ++n) {
            int col = n * 32 + l31;
            float iv = gamma[col] * rsqrtf(var[col] + EPS_BN);
            float bb = beta[col] - mean[col] * iv;
            const f32x16& A = m == 0 ? (n == 0 ? acc0 : acc1) : (n == 0 ? acc2 : acc3);
#pragma unroll
            for (int i = 0; i < 16; ++i) {
                long oo = o0 + m * 32 + (i & 3) + 8 * (i >> 2) + 4 * lhi;
                if (oo < n_down)
                    out[oo * 64 + col] = fmaxf(A[i] * iv + bb, 0.f);
            }
        }
#undef LDI
#undef GATH
#undef LDB
#undef COMPUTE
}

extern "C" void kernel_launch(void* const* d_in, const int* in_sizes, int n_args,
                              void* d_out, int out_size, void* d_ws, size_t ws_size,
                              hipStream_t stream) {
    const float* feat    = (const float*)d_in[0];
    const float* w_down  = (const float*)d_in[1];
    const float* gamma_d = (const float*)d_in[2];
    const float* beta_d  = (const float*)d_in[3];
    const float* mean_d  = (const float*)d_in[4];
    const float* var_d   = (const float*)d_in[5];
    const float* w_ref   = (const float*)d_in[6];
    const float* gamma_r = (const float*)d_in[7];
    const float* beta_r  = (const float*)d_in[8];
    const float* mean_r  = (const float*)d_in[9];
    const float* var_r   = (const float*)d_in[10];
    const int*   gather_d  = (const int*)d_in[11];
    const int*   scatter_d = (const int*)d_in[12];
    const int*   gather_r  = (const int*)d_in[13];
    const int*   scatter_r = (const int*)d_in[14];

    int n_in   = in_sizes[0] / 32;
    int md     = in_sizes[11] / 16;
    int mr     = in_sizes[13] / 81;
    int n_down = out_size / 64;

    // ws: ybf[(n_down+1)*64]bf16 | featbf[(n_in+1)*32]bf16 | wt[81*4096]bf16 |
    //     wtd[16*2048]bf16 | invr[81*n_down]i32 | invd[16*n_down]i32 (contig for memset)
    char* ws = (char*)d_ws;
    size_t off = 0;
    auto alloc = [&](size_t bytes) { char* p = ws + off; off = (off + bytes + 255) & ~(size_t)255; return p; };
    unsigned short* ybf    = (unsigned short*)alloc((size_t)(n_down + 1) * 64 * 2);
    unsigned short* featbf = (unsigned short*)alloc((size_t)(n_in + 1) * 32 * 2);
    unsigned short* wt     = (unsigned short*)alloc((size_t)81 * 4096 * 2);
    unsigned short* wtd    = (unsigned short*)alloc((size_t)16 * 2048 * 2);
    int* invr = (int*)(ws + off);
    int* invd = invr + (size_t)81 * n_down;

    hipMemsetAsync(invr, 0xFF, (size_t)97 * n_down * sizeof(int), stream);

    long td = 16L * md;
    build_inv<<<(int)((td + 255) / 256), 256, 0, stream>>>(gather_d, scatter_d, td, md, invd, n_down);
    long tr = 81L * mr;
    build_inv<<<(int)((tr + 255) / 256), 256, 0, stream>>>(gather_r, scatter_r, tr, mr, invr, n_down);

    long ft = ((long)n_in * 32 + 32) / 4;
    fcvt<<<(int)((ft + 255) / 256), 256, 0, stream>>>(feat, featbf, ybf + (size_t)n_down * 64, n_in);
    wcvt_r<<<81 * 4096 / 256, 256, 0, stream>>>(w_ref, wt);
    wcvt_d<<<16 * 2048 / 256, 256, 0, stream>>>(w_down, wtd);

    long wavesD  = ((long)n_down + 31) / 32;
    int  blocksD = (int)((wavesD * 64 + 255) / 256);
    conv_down_mfma<<<blocksD, 256, 0, stream>>>(featbf, wtd, invd,
                                                gamma_d, beta_d, mean_d, var_d,
                                                ybf, n_down, n_in);

    long wavesR  = ((long)n_down + 63) / 64;
    int  blocksR = (int)((wavesR + 3) / 4);
    conv_ref_mfma<<<blocksR, 256, 0, stream>>>(ybf, wt, invr,
                                               gamma_r, beta_r, mean_r, var_r,
                                               (float*)d_out, n_down, blocksR);
}

// Round 7
// 462.976 us; speedup vs baseline: 1.1187x; 1.1187x over previous
//
#include <hip/hip_runtime.h>
#include <hip/hip_bf16.h>
#include <cstdint>

#define EPS_BN 1e-5f

typedef __attribute__((ext_vector_type(8)))  short bf16x8;   // 8 bf16 = 4 VGPRs
typedef __attribute__((ext_vector_type(16))) float f32x16;   // MFMA 32x32 acc
typedef __attribute__((ext_vector_type(4)))  unsigned short u16x4;

#define MFMA32(a, b, c) __builtin_amdgcn_mfma_f32_32x32x16_bf16(a, b, c, 0, 0, 0)

// async global->LDS, 16B/lane: per-lane GLOBAL src, LDS dst = uniform base + lane*16
#define GLOAD_LDS16(gsrc, ldst) \
    __builtin_amdgcn_global_load_lds((const __attribute__((address_space(1))) void*)(gsrc), \
                                     (__attribute__((address_space(3))) void*)(ldst), 16, 0, 0)

// ---------------------------------------------------------------------------
// build transposed inverted map: invT[k*n_down + s] = g  (s unique per k).
// Table pre-memset to 0xFF (-1 = miss).
// ---------------------------------------------------------------------------
__global__ void build_inv(const int* __restrict__ gather, const int* __restrict__ scatter,
                          long total, int m, int* __restrict__ invT, int n_down) {
    long i = (long)blockIdx.x * blockDim.x + threadIdx.x;
    if (i >= total) return;
    int s = scatter[i];
    if (s < n_down) {
        int k = (int)(i / m);
        invT[(long)k * n_down + s] = gather[i];
    }
}

// feat f32[n_in][32] -> bf16 [n_in+1][32] (pad row zero); also zero ybf pad row.
__global__ void fcvt(const float* __restrict__ f, unsigned short* __restrict__ fb,
                     unsigned short* __restrict__ ybf_pad, long n_in) {
    long t = (long)blockIdx.x * blockDim.x + threadIdx.x;
    long e = t * 4;
    long total = n_in * 32;
    if (e < total) {
        float4 v = *(const float4*)(f + e);
        u16x4 o;
        __hip_bfloat16 h;
        h = __float2bfloat16(v.x); o.x = *(unsigned short*)&h;
        h = __float2bfloat16(v.y); o.y = *(unsigned short*)&h;
        h = __float2bfloat16(v.z); o.z = *(unsigned short*)&h;
        h = __float2bfloat16(v.w); o.w = *(unsigned short*)&h;
        *(u16x4*)(fb + e) = o;
    } else if (e < total + 32) {
        u16x4 z = {0, 0, 0, 0};
        *(u16x4*)(fb + e) = z;
    }
    if (blockIdx.x == 0 && threadIdx.x < 16) {
        u16x4 z = {0, 0, 0, 0};
        ((u16x4*)ybf_pad)[threadIdx.x] = z;
    }
}

// w_ref f32[81][64cin][64cout] -> bf16 wt[k][kq(4)][col(64)][16]: slot
// (col, lhi*8+j) of kq holds w[cin = kq*16+lhi*8+j][col] -> one coalesced b128
// per (kq, ntile) B-fragment load.
__global__ void wcvt_r(const float* __restrict__ w, unsigned short* __restrict__ wt) {
    int e = blockIdx.x * 256 + threadIdx.x;      // 81*4096
    int k = e >> 12, r = e & 4095;
    int cin = ((r >> 10) << 4) + (r & 15);
    int col = (r >> 4) & 63;
    __hip_bfloat16 h = __float2bfloat16(w[(k << 12) + (cin << 6) + col]);
    wt[e] = *(unsigned short*)&h;
}

// w_down f32[16][32cin][64cout] -> bf16 wtd[k][kq(2)][col(64)][16]
__global__ void wcvt_d(const float* __restrict__ w, unsigned short* __restrict__ wt) {
    int e = blockIdx.x * 256 + threadIdx.x;      // 16*2048
    int k = e >> 11, r = e & 2047;
    int cin = ((r >> 10) << 4) + (r & 15);
    int col = (r >> 4) & 63;
    __hip_bfloat16 h = __float2bfloat16(w[(k << 11) + (cin << 6) + col]);
    wt[e] = *(unsigned short*)&h;
}

// ---------------------------------------------------------------------------
// Stage 1: MFMA bf16, K=32, one wave = 32 rows. 91% pad-row gathers (L1-hot).
// ---------------------------------------------------------------------------
__global__ __launch_bounds__(256, 4) void conv_down_mfma(
        const unsigned short* __restrict__ fb, const unsigned short* __restrict__ wtd,
        const int* __restrict__ invd,
        const float* __restrict__ gamma, const float* __restrict__ beta,
        const float* __restrict__ mean, const float* __restrict__ var,
        unsigned short* __restrict__ y, int n_down, int n_in) {
    int  tid  = threadIdx.x;
    int  lane = tid & 63, l31 = lane & 31, lhi = lane >> 5;
    long wv   = ((long)blockIdx.x * 256 + tid) >> 6;
    long o0   = wv * 32;
    if (o0 >= n_down) return;

    int  oA = (int)(o0 + l31 < n_down ? o0 + l31 : n_down - 1);
    const short* ysb = (const short*)fb;

#define LDI_D(k) invd[(size_t)(k) * n_down + oA]
#define GATH_D(dst, g) { \
        const short* p = ysb + (size_t)((g) < 0 ? n_in : (g)) * 32 + lhi * 8; \
        dst[0] = *(const bf16x8*)p; dst[1] = *(const bf16x8*)(p + 16); }

    int g0 = LDI_D(0), gq1 = LDI_D(1), gq2 = LDI_D(2);
    bf16x8 ac[2];
    GATH_D(ac, g0);
    f32x16 acc0 = {}, acc1 = {};
    const short* wp = (const short*)wtd + l31 * 16 + lhi * 8;

    for (int k = 0; k < 16; ++k) {
        int gN = (k < 13) ? LDI_D(k + 3) : -1;
        bf16x8 an[2];
        GATH_D(an, gq1);
        const short* wk = wp + k * 2048;
#pragma unroll
        for (int kq = 0; kq < 2; ++kq) {
            bf16x8 b0 = *(const bf16x8*)(wk + kq * 1024);
            bf16x8 b1 = *(const bf16x8*)(wk + kq * 1024 + 512);
            acc0 = MFMA32(ac[kq], b0, acc0);
            acc1 = MFMA32(ac[kq], b1, acc1);
        }
        ac[0] = an[0]; ac[1] = an[1];
        gq1 = gq2; gq2 = gN;
    }

#pragma unroll
    for (int n = 0; n < 2; ++n) {
        int col = n * 32 + l31;
        float iv = gamma[col] * rsqrtf(var[col] + EPS_BN);
        float bb = beta[col] - mean[col] * iv;
        const f32x16& A = n ? acc1 : acc0;
#pragma unroll
        for (int i = 0; i < 16; ++i) {
            long oo = o0 + (i & 3) + 8 * (i >> 2) + 4 * lhi;
            if (oo < n_down) {
                __hip_bfloat16 h = __float2bfloat16(fmaxf(A[i] * iv + bb, 0.f));
                y[oo * 64 + col] = *(unsigned short*)&h;
            }
        }
    }
#undef LDI_D
#undef GATH_D
}

// ---------------------------------------------------------------------------
// Stage 2: MFMA bf16, wave = 32 rows x 64 cols, 81 offsets. R4 structure
// (best measured) at 1.5x occupancy: A via per-wave double-buffered LDS
// (global_load_lds, pre-swizzled per-lane src); B global->reg dbuf (named
// sets); barrier-free, counted vmcnt(16)/region. idx via per-lane BROADCAST
// loads (no shfl/bpermute on the LDS pipe), dist-2 prefetch queue.
// Footprint: 32 AGPR acc + ~110 VGPR + 8KB LDS -> 3 waves/SIMD (12/CU).
// ---------------------------------------------------------------------------
__global__ __launch_bounds__(256, 3) void conv_ref_mfma(
        const unsigned short* __restrict__ ybf, const unsigned short* __restrict__ wt,
        const int* __restrict__ invr,
        const float* __restrict__ gamma, const float* __restrict__ beta,
        const float* __restrict__ mean, const float* __restrict__ var,
        float* __restrict__ out, int n_down, int nwg) {
    __shared__ char ldsA[4][2][4096];            // [wave][buf][32 rows x 128B]

    // bijective XCD swizzle (m204)
    int bid = blockIdx.x;
    int q = nwg >> 3, r = nwg & 7;
    int xcd = bid & 7, pos = bid >> 3;
    int swzb = (xcd < r ? xcd * (q + 1) : r * (q + 1) + (xcd - r) * q) + pos;

    const int tid  = threadIdx.x;
    const int lane = tid & 63, l31 = lane & 31, lhi = lane >> 5;
    const int wid  = tid >> 6;
    const long o0  = ((long)swzb * 4 + wid) * 32;
    if (o0 >= n_down) return;                    // barrier-free: early return safe

    const char* ybase = (const char*)ybf;
    char* ldsw = &ldsA[wid][0][0];
    // stage-instr i covers rows i*8+(lane>>3); src slot ((lane&7) ^ row&7)*16
    const int ro  = lane >> 3;                   // 0..7
    const int swz = (((lane & 7) ^ ro) << 4);

    // per-lane clamped idx addresses for the 4 broadcast loads (instr i -> row i*8+ro)
    int oI0 = (int)(o0 + 0  + ro < n_down ? o0 + 0  + ro : n_down - 1);
    int oI1 = (int)(o0 + 8  + ro < n_down ? o0 + 8  + ro : n_down - 1);
    int oI2 = (int)(o0 + 16 + ro < n_down ? o0 + 16 + ro : n_down - 1);
    int oI3 = (int)(o0 + 24 + ro < n_down ? o0 + 24 + ro : n_down - 1);

#define LDI(k, Q) { const int* p_ = invr + (size_t)(k) * n_down; \
        Q##0 = p_[oI0]; Q##1 = p_[oI1]; Q##2 = p_[oI2]; Q##3 = p_[oI3]; }

#define STAGE(buf, Q) { \
        size_t r0_ = (size_t)(Q##0 < 0 ? n_down : Q##0); \
        size_t r1_ = (size_t)(Q##1 < 0 ? n_down : Q##1); \
        size_t r2_ = (size_t)(Q##2 < 0 ? n_down : Q##2); \
        size_t r3_ = (size_t)(Q##3 < 0 ? n_down : Q##3); \
        GLOAD_LDS16(ybase + r0_ * 128 + swz, ldsw + (buf) * 4096); \
        GLOAD_LDS16(ybase + r1_ * 128 + swz, ldsw + (buf) * 4096 + 1024); \
        GLOAD_LDS16(ybase + r2_ * 128 + swz, ldsw + (buf) * 4096 + 2048); \
        GLOAD_LDS16(ybase + r3_ * 128 + swz, ldsw + (buf) * 4096 + 3072); }

#define LDB(B, k) { \
        const short* wk_ = wp + (size_t)(k) * 4096; \
        _Pragma("unroll") \
        for (int kq = 0; kq < 4; ++kq) { \
            B##0[kq] = *(const bf16x8*)(wk_ + kq * 1024); \
            B##1[kq] = *(const bf16x8*)(wk_ + kq * 1024 + 512); } }

    const int rsw   = (l31 & 7) << 4;
    const int rowA  = l31 * 128;
    const int lhi16 = lhi * 16;

#define COMPUTE(buf, B) { \
        const char* la = ldsw + (buf) * 4096; \
        __builtin_amdgcn_s_setprio(1); \
        _Pragma("unroll") \
        for (int kq = 0; kq < 4; ++kq) { \
            int fo = (kq * 32 + lhi16) ^ rsw; \
            bf16x8 a_ = *(const bf16x8*)(la + rowA + fo); \
            acc0 = MFMA32(a_, B##0[kq], acc0); \
            acc1 = MFMA32(a_, B##1[kq], acc1); } \
        __builtin_amdgcn_s_setprio(0); }

#define WAITR { asm volatile("s_waitcnt vmcnt(16)" ::: "memory"); \
                __builtin_amdgcn_sched_barrier(0); }

    f32x16 acc0 = {}, acc1 = {};
    const short* wp = (const short*)wt + l31 * 16 + lhi * 8;
    bf16x8 Bc0[4], Bc1[4], Bn0[4], Bn1[4];
    int qA0, qA1, qA2, qA3;                      // idx[k+1]
    int qB0, qB1, qB2, qB3;                      // idx[k+2]
    int t0, t1, t2, t3, u0, u1, u2, u3;

    // prologue: idx[0..2]; stage A[0]; B[0]
    LDI(0, t);                                   // 4
    LDI(1, qA);                                  // 4
    LDI(2, qB);                                  // 4
    asm volatile("s_waitcnt vmcnt(8)" ::: "memory");   // idx[0] ready
    __builtin_amdgcn_sched_barrier(0);
    STAGE(0, t);                                 // 4
    LDB(Bc, 0);                                  // 8   (outstanding ~20)

    // main loop: regions k (even: buf0->compute, stage buf1) and k+1
    for (int k = 0; k < 80; k += 2) {
        // region k
        LDI(k + 3, t);                           // idx queue tail
        STAGE(1, qA);                            // A[k+1] (compiler waits idx[k+1], loaded 2 regions ago)
        LDB(Bn, k + 1);
        WAITR;                                   // A[k], B[k] resident
        COMPUTE(0, Bc);
        // region k+1
        LDI(k + 4, u);
        STAGE(0, qB);                            // A[k+2]
        LDB(Bc, k + 2);
        WAITR;
        COMPUTE(1, Bn);
        qA0 = t0; qA1 = t1; qA2 = t2; qA3 = t3;  // -> idx[k+3]
        qB0 = u0; qB1 = u1; qB2 = u2; qB3 = u3;  // -> idx[k+4]
    }
    // region 80 (A[80] in buf0, B[80] in Bc)
    asm volatile("s_waitcnt vmcnt(0)" ::: "memory");
    __builtin_amdgcn_sched_barrier(0);
    COMPUTE(0, Bc);

    // epilogue: BN + ReLU, f32 out
#pragma unroll
    for (int n = 0; n < 2; ++n) {
        int col = n * 32 + l31;
        float iv = gamma[col] * rsqrtf(var[col] + EPS_BN);
        float bb = beta[col] - mean[col] * iv;
        const f32x16& A = n == 0 ? acc0 : acc1;
#pragma unroll
        for (int i = 0; i < 16; ++i) {
            long oo = o0 + (i & 3) + 8 * (i >> 2) + 4 * lhi;
            if (oo < n_down)
                out[oo * 64 + col] = fmaxf(A[i] * iv + bb, 0.f);
        }
    }
#undef LDI
#undef STAGE
#undef LDB
#undef COMPUTE
#undef WAITR
}

extern "C" void kernel_launch(void* const* d_in, const int* in_sizes, int n_args,
                              void* d_out, int out_size, void* d_ws, size_t ws_size,
                              hipStream_t stream) {
    const float* feat    = (const float*)d_in[0];
    const float* w_down  = (const float*)d_in[1];
    const float* gamma_d = (const float*)d_in[2];
    const float* beta_d  = (const float*)d_in[3];
    const float* mean_d  = (const float*)d_in[4];
    const float* var_d   = (const float*)d_in[5];
    const float* w_ref   = (const float*)d_in[6];
    const float* gamma_r = (const float*)d_in[7];
    const float* beta_r  = (const float*)d_in[8];
    const float* mean_r  = (const float*)d_in[9];
    const float* var_r   = (const float*)d_in[10];
    const int*   gather_d  = (const int*)d_in[11];
    const int*   scatter_d = (const int*)d_in[12];
    const int*   gather_r  = (const int*)d_in[13];
    const int*   scatter_r = (const int*)d_in[14];

    int n_in   = in_sizes[0] / 32;
    int md     = in_sizes[11] / 16;
    int mr     = in_sizes[13] / 81;
    int n_down = out_size / 64;

    // ws: ybf[(n_down+1)*64]bf16 | featbf[(n_in+1)*32]bf16 | wt[81*4096]bf16 |
    //     wtd[16*2048]bf16 | invr[81*n_down]i32 | invd[16*n_down]i32 (contig for memset)
    char* ws = (char*)d_ws;
    size_t off = 0;
    auto alloc = [&](size_t bytes) { char* p = ws + off; off = (off + bytes + 255) & ~(size_t)255; return p; };
    unsigned short* ybf    = (unsigned short*)alloc((size_t)(n_down + 1) * 64 * 2);
    unsigned short* featbf = (unsigned short*)alloc((size_t)(n_in + 1) * 32 * 2);
    unsigned short* wt     = (unsigned short*)alloc((size_t)81 * 4096 * 2);
    unsigned short* wtd    = (unsigned short*)alloc((size_t)16 * 2048 * 2);
    int* invr = (int*)(ws + off);
    int* invd = invr + (size_t)81 * n_down;

    hipMemsetAsync(invr, 0xFF, (size_t)97 * n_down * sizeof(int), stream);

    long td = 16L * md;
    build_inv<<<(int)((td + 255) / 256), 256, 0, stream>>>(gather_d, scatter_d, td, md, invd, n_down);
    long tr = 81L * mr;
    build_inv<<<(int)((tr + 255) / 256), 256, 0, stream>>>(gather_r, scatter_r, tr, mr, invr, n_down);

    long ft = ((long)n_in * 32 + 32) / 4;
    fcvt<<<(int)((ft + 255) / 256), 256, 0, stream>>>(feat, featbf, ybf + (size_t)n_down * 64, n_in);
    wcvt_r<<<81 * 4096 / 256, 256, 0, stream>>>(w_ref, wt);
    wcvt_d<<<16 * 2048 / 256, 256, 0, stream>>>(w_down, wtd);

    long wavesD  = ((long)n_down + 31) / 32;
    int  blocksD = (int)((wavesD * 64 + 255) / 256);
    conv_down_mfma<<<blocksD, 256, 0, stream>>>(featbf, wtd, invd,
                                                gamma_d, beta_d, mean_d, var_d,
                                                ybf, n_down, n_in);

    int blocksR = (n_down + 127) / 128;
    conv_ref_mfma<<<blocksR, 256, 0, stream>>>(ybf, wt, invr,
                                               gamma_r, beta_r, mean_r, var_r,
                                               (float*)d_out, n_down, blocksR);
}